// Round 1
// baseline (448.851 us; speedup 1.0000x reference)
//
#include <hip/hip_runtime.h>
#include <stdint.h>

#define B_ 32
#define S_ 8192
#define D_ 256
#define Q_ 256
#define U_ 128

typedef float floatx4 __attribute__((ext_vector_type(4)));
typedef float f32x4 __attribute__((ext_vector_type(4)));
typedef __bf16 bf16x8 __attribute__((ext_vector_type(8)));
typedef unsigned short ushortx4 __attribute__((ext_vector_type(4)));

static __device__ __forceinline__ unsigned short f2bf(float f) {
    unsigned int x = __builtin_bit_cast(unsigned int, f);
    x += 0x7FFFu + ((x >> 16) & 1u);   // RNE (inputs are finite/normal)
    return (unsigned short)(x >> 16);
}

static __device__ __forceinline__ float fast_tanh(float x) {
    x = fminf(15.f, fmaxf(-15.f, x));
    float e = __expf(2.f * x);
    return __fdividef(e - 1.f, e + 1.f);
}

// Kernel 1: proj_q[b][u] = sum_q query[b][q]*W2[q][u]; also W1^T -> bf16 in ws.
__global__ __launch_bounds__(128) void prep_kernel(
        const float* __restrict__ query, const float* __restrict__ W1,
        const float* __restrict__ W2, float* __restrict__ pq,
        unsigned short* __restrict__ w1t) {
    int b = blockIdx.x;
    int t = threadIdx.x;  // 0..127
    __shared__ float qrow[Q_];
    qrow[t] = query[b * Q_ + t];
    qrow[t + 128] = query[b * Q_ + 128 + t];
    __syncthreads();
    float acc = 0.f;
#pragma unroll 8
    for (int q = 0; q < Q_; ++q) acc = fmaf(qrow[q], W2[q * U_ + t], acc);
    pq[b * U_ + t] = acc;
    // W1T element e = n*256 + k ; this block covers e in [b*1024, b*1024+1024)
    int base = (b * 128 + t) * 8;
#pragma unroll
    for (int j = 0; j < 8; ++j) {
        int e = base + j;
        int n = e >> 8, k = e & 255;
        w1t[e] = f2bf(W1[k * U_ + n]);
    }
}

// Kernel 2: scores[b][s] = sum_u V[u]*tanh(proj_v[s][u] + pq[b][u])
// 128x128 MFMA tile per block (M=s, N=u=128), K=D=256, BK=32.
__global__ __launch_bounds__(256) void scores_kernel(
        const float* __restrict__ values, const unsigned short* __restrict__ w1t,
        const float* __restrict__ pq, const float* __restrict__ V,
        float* __restrict__ scores) {
    __shared__ unsigned short As[128 * 40];  // padded stride 40 (2-way bank alias = free)
    __shared__ unsigned short Bs[128 * 40];
    __shared__ float part[256];

    int b = blockIdx.y;
    int s0 = blockIdx.x * 128;
    int tid = threadIdx.x;
    int lane = tid & 63;
    int wave = tid >> 6;
    int wr = wave >> 1, wc = wave & 1;
    int cc = lane & 15, qg = lane >> 4;

    const float* vb = values + ((size_t)b * S_ + s0) * D_;

    f32x4 acc[4][4];
#pragma unroll
    for (int mt = 0; mt < 4; ++mt)
#pragma unroll
        for (int nt = 0; nt < 4; ++nt) acc[mt][nt] = (f32x4){0.f, 0.f, 0.f, 0.f};

    for (int kt = 0; kt < 8; ++kt) {
        int k0 = kt * 32;
        __syncthreads();
#pragma unroll
        for (int i = 0; i < 4; ++i) {
            int idx = tid + i * 256;      // 1024 float4 chunks of the 128x32 A tile
            int row = idx >> 3, c = idx & 7;
            floatx4 v = *reinterpret_cast<const floatx4*>(vb + (size_t)row * D_ + k0 + c * 4);
            ushortx4 u;
            u[0] = f2bf(v[0]); u[1] = f2bf(v[1]); u[2] = f2bf(v[2]); u[3] = f2bf(v[3]);
            *reinterpret_cast<ushortx4*>(&As[row * 40 + c * 4]) = u;
            ushortx4 w = *reinterpret_cast<const ushortx4*>(&w1t[row * 256 + k0 + c * 4]);
            *reinterpret_cast<ushortx4*>(&Bs[row * 40 + c * 4]) = w;
        }
        __syncthreads();
        bf16x8 af[4], bfr[4];
#pragma unroll
        for (int mt = 0; mt < 4; ++mt)
            af[mt] = *reinterpret_cast<const bf16x8*>(&As[(wr * 64 + mt * 16 + cc) * 40 + qg * 8]);
#pragma unroll
        for (int nt = 0; nt < 4; ++nt)
            bfr[nt] = *reinterpret_cast<const bf16x8*>(&Bs[(wc * 64 + nt * 16 + cc) * 40 + qg * 8]);
#pragma unroll
        for (int mt = 0; mt < 4; ++mt)
#pragma unroll
            for (int nt = 0; nt < 4; ++nt)
                acc[mt][nt] = __builtin_amdgcn_mfma_f32_16x16x32_bf16(af[mt], bfr[nt], acc[mt][nt], 0, 0, 0);
    }

    // Epilogue: per lane, 4 u-columns (one per nt), 16 rows (mt x reg).
    float Vu[4], pqu[4];
#pragma unroll
    for (int nt = 0; nt < 4; ++nt) {
        int u = wc * 64 + nt * 16 + cc;
        Vu[nt] = V[u];
        pqu[nt] = pq[b * U_ + u];
    }
#pragma unroll
    for (int mt = 0; mt < 4; ++mt) {
#pragma unroll
        for (int r = 0; r < 4; ++r) {
            float s = 0.f;
#pragma unroll
            for (int nt = 0; nt < 4; ++nt)
                s += Vu[nt] * fast_tanh(acc[mt][nt][r] + pqu[nt]);
            // reduce across the 16 lanes (same qg group) holding different u
            s += __shfl_xor(s, 1);
            s += __shfl_xor(s, 2);
            s += __shfl_xor(s, 4);
            s += __shfl_xor(s, 8);
            if (cc == 0) part[wc * 128 + wr * 64 + mt * 16 + qg * 4 + r] = s;
        }
    }
    __syncthreads();
    if (tid < 128)
        scores[(size_t)b * S_ + s0 + tid] = part[tid] + part[128 + tid];
}

// Kernel 3: softmax over S per batch; write weights to out[8192 + b*S + s].
__global__ __launch_bounds__(256) void softmax_kernel(
        const float* __restrict__ scores, float* __restrict__ out) {
    int b = blockIdx.x;
    int tid = threadIdx.x;  // 256
    const floatx4* sc = reinterpret_cast<const floatx4*>(scores + (size_t)b * S_);
    floatx4 v[8];
    float m = -1e30f;
#pragma unroll
    for (int i = 0; i < 8; ++i) {
        v[i] = sc[tid + i * 256];
        m = fmaxf(m, fmaxf(fmaxf(v[i][0], v[i][1]), fmaxf(v[i][2], v[i][3])));
    }
#pragma unroll
    for (int off = 32; off >= 1; off >>= 1) m = fmaxf(m, __shfl_xor(m, off));
    __shared__ float red[4];
    __shared__ float red2[4];
    if ((tid & 63) == 0) red[tid >> 6] = m;
    __syncthreads();
    m = fmaxf(fmaxf(red[0], red[1]), fmaxf(red[2], red[3]));
    float lsum = 0.f;
#pragma unroll
    for (int i = 0; i < 8; ++i) {
#pragma unroll
        for (int j = 0; j < 4; ++j) {
            v[i][j] = __expf(v[i][j] - m);
            lsum += v[i][j];
        }
    }
#pragma unroll
    for (int off = 32; off >= 1; off >>= 1) lsum += __shfl_xor(lsum, off);
    if ((tid & 63) == 0) red2[tid >> 6] = lsum;
    __syncthreads();
    float inv = 1.f / (red2[0] + red2[1] + red2[2] + red2[3]);
    floatx4* wout = reinterpret_cast<floatx4*>(out + B_ * D_ + (size_t)b * S_);
#pragma unroll
    for (int i = 0; i < 8; ++i) wout[tid + i * 256] = v[i] * inv;
}

// Kernel 4: context[b][d] = sum_s w[b][s]*values[b][s][d]
__global__ __launch_bounds__(256) void context_kernel(
        const float* __restrict__ values, const float* __restrict__ weights,
        float* __restrict__ ctx) {
    int b = blockIdx.x;
    int chunk = blockIdx.y;  // 32 chunks of 256 s-rows
    int tid = threadIdx.x;
    int g = tid & 63, sub = tid >> 6;
    const float* vb = values + (size_t)b * S_ * D_;
    const float* wb = weights + (size_t)b * S_;
    floatx4 acc = {0.f, 0.f, 0.f, 0.f};
    int s0 = chunk * 256;
    for (int s = s0 + sub; s < s0 + 256; s += 4) {
        float w = wb[s];
        floatx4 v = *reinterpret_cast<const floatx4*>(vb + (size_t)s * D_ + g * 4);
        acc += v * w;
    }
    __shared__ floatx4 cbuf[256];
    cbuf[tid] = acc;
    __syncthreads();
    if (tid < 64) {
        floatx4 r = cbuf[tid] + cbuf[tid + 64] + cbuf[tid + 128] + cbuf[tid + 192];
        atomicAdd(&ctx[b * D_ + g * 4 + 0], r[0]);
        atomicAdd(&ctx[b * D_ + g * 4 + 1], r[1]);
        atomicAdd(&ctx[b * D_ + g * 4 + 2], r[2]);
        atomicAdd(&ctx[b * D_ + g * 4 + 3], r[3]);
    }
}

extern "C" void kernel_launch(void* const* d_in, const int* in_sizes, int n_in,
                              void* d_out, int out_size, void* d_ws, size_t ws_size,
                              hipStream_t stream) {
    const float* query  = (const float*)d_in[0];
    const float* values = (const float*)d_in[1];
    const float* W1     = (const float*)d_in[2];
    const float* W2     = (const float*)d_in[3];
    const float* V      = (const float*)d_in[4];
    float* out = (float*)d_out;

    unsigned short* w1t = (unsigned short*)d_ws;                      // 65536 B
    float* pq     = (float*)((char*)d_ws + 65536);                    // 16384 B
    float* scores = (float*)((char*)d_ws + 65536 + 16384);            // 1 MiB

    // zero the context region (d_out is poisoned each call)
    hipMemsetAsync(out, 0, B_ * D_ * sizeof(float), stream);

    prep_kernel<<<dim3(32), dim3(128), 0, stream>>>(query, W1, W2, pq, w1t);
    scores_kernel<<<dim3(S_ / 128, B_), dim3(256), 0, stream>>>(values, w1t, pq, V, scores);
    softmax_kernel<<<dim3(B_), dim3(256), 0, stream>>>(scores, out);
    context_kernel<<<dim3(B_, 32), dim3(256), 0, stream>>>(values, out + B_ * D_, out);
}

// Round 2
// 428.533 us; speedup vs baseline: 1.0474x; 1.0474x over previous
//
#include <hip/hip_runtime.h>
#include <stdint.h>

#define B_ 32
#define S_ 8192
#define D_ 256
#define Q_ 256
#define U_ 128
#define NCHUNK 64   // S_/128 chunks per batch

typedef float floatx4 __attribute__((ext_vector_type(4)));
typedef float f32x4 __attribute__((ext_vector_type(4)));
typedef __bf16 bf16x8 __attribute__((ext_vector_type(8)));
typedef unsigned short ushortx4 __attribute__((ext_vector_type(4)));

static __device__ __forceinline__ unsigned short f2bf(float f) {
    unsigned int x = __builtin_bit_cast(unsigned int, f);
    x += 0x7FFFu + ((x >> 16) & 1u);   // RNE (inputs are finite/normal)
    return (unsigned short)(x >> 16);
}

static __device__ __forceinline__ float fast_tanh(float x) {
    x = fminf(15.f, fmaxf(-15.f, x));
    float e = __expf(2.f * x);
    return __fdividef(e - 1.f, e + 1.f);
}

// Kernel 1: proj_q[b][u] = sum_q query[b][q]*W2[q][u]; also W1^T -> bf16 in ws.
__global__ __launch_bounds__(128) void prep_kernel(
        const float* __restrict__ query, const float* __restrict__ W1,
        const float* __restrict__ W2, float* __restrict__ pq,
        unsigned short* __restrict__ w1t) {
    int b = blockIdx.x;
    int t = threadIdx.x;  // 0..127
    __shared__ float qrow[Q_];
    qrow[t] = query[b * Q_ + t];
    qrow[t + 128] = query[b * Q_ + 128 + t];
    __syncthreads();
    float acc = 0.f;
#pragma unroll 8
    for (int q = 0; q < Q_; ++q) acc = fmaf(qrow[q], W2[q * U_ + t], acc);
    pq[b * U_ + t] = acc;
    int base = (b * 128 + t) * 8;
#pragma unroll
    for (int j = 0; j < 8; ++j) {
        int e = base + j;
        int n = e >> 8, k = e & 255;
        w1t[e] = f2bf(W1[k * U_ + n]);
    }
}

// Kernel 2 (fused): per (b, 128-row chunk):
//   scores via MFMA -> raw scores to ws; local max m, p=exp(s-m), sum l;
//   partial context sum_s p_s * values[s,:] -> cpart.  ONE HBM pass over values.
__global__ __launch_bounds__(256) void fused_kernel(
        const float* __restrict__ values, const unsigned short* __restrict__ w1t,
        const float* __restrict__ pq, const float* __restrict__ V,
        float* __restrict__ scores, float* __restrict__ mbuf,
        float* __restrict__ lbuf, float* __restrict__ cpart) {
    __shared__ unsigned short As[128 * 40];  // padded stride 40 (2-way alias = free)
    __shared__ unsigned short Bs[128 * 40];
    __shared__ float part[256];
    __shared__ float sarr[128];
    __shared__ float parr[128];
    __shared__ float redm[1];
    __shared__ floatx4 cbuf[256];

    int b = blockIdx.y;
    int cid = blockIdx.x;
    int s0 = cid * 128;
    int tid = threadIdx.x;
    int lane = tid & 63;
    int wave = tid >> 6;
    int wr = wave >> 1, wc = wave & 1;
    int cc = lane & 15, qg = lane >> 4;

    const float* vb = values + ((size_t)b * S_ + s0) * D_;

    f32x4 acc[4][4];
#pragma unroll
    for (int mt = 0; mt < 4; ++mt)
#pragma unroll
        for (int nt = 0; nt < 4; ++nt) acc[mt][nt] = (f32x4){0.f, 0.f, 0.f, 0.f};

    for (int kt = 0; kt < 8; ++kt) {
        int k0 = kt * 32;
        __syncthreads();
#pragma unroll
        for (int i = 0; i < 4; ++i) {
            int idx = tid + i * 256;
            int row = idx >> 3, c = idx & 7;
            floatx4 v = *reinterpret_cast<const floatx4*>(vb + (size_t)row * D_ + k0 + c * 4);
            ushortx4 u;
            u[0] = f2bf(v[0]); u[1] = f2bf(v[1]); u[2] = f2bf(v[2]); u[3] = f2bf(v[3]);
            *reinterpret_cast<ushortx4*>(&As[row * 40 + c * 4]) = u;
            ushortx4 w = *reinterpret_cast<const ushortx4*>(&w1t[row * 256 + k0 + c * 4]);
            *reinterpret_cast<ushortx4*>(&Bs[row * 40 + c * 4]) = w;
        }
        __syncthreads();
        bf16x8 af[4], bfr[4];
#pragma unroll
        for (int mt = 0; mt < 4; ++mt)
            af[mt] = *reinterpret_cast<const bf16x8*>(&As[(wr * 64 + mt * 16 + cc) * 40 + qg * 8]);
#pragma unroll
        for (int nt = 0; nt < 4; ++nt)
            bfr[nt] = *reinterpret_cast<const bf16x8*>(&Bs[(wc * 64 + nt * 16 + cc) * 40 + qg * 8]);
#pragma unroll
        for (int mt = 0; mt < 4; ++mt)
#pragma unroll
            for (int nt = 0; nt < 4; ++nt)
                acc[mt][nt] = __builtin_amdgcn_mfma_f32_16x16x32_bf16(af[mt], bfr[nt], acc[mt][nt], 0, 0, 0);
    }

    // tanh + dot-V epilogue -> per-row score partials
    float Vu[4], pqu[4];
#pragma unroll
    for (int nt = 0; nt < 4; ++nt) {
        int u = wc * 64 + nt * 16 + cc;
        Vu[nt] = V[u];
        pqu[nt] = pq[b * U_ + u];
    }
#pragma unroll
    for (int mt = 0; mt < 4; ++mt) {
#pragma unroll
        for (int r = 0; r < 4; ++r) {
            float s = 0.f;
#pragma unroll
            for (int nt = 0; nt < 4; ++nt)
                s += Vu[nt] * fast_tanh(acc[mt][nt][r] + pqu[nt]);
            s += __shfl_xor(s, 1);
            s += __shfl_xor(s, 2);
            s += __shfl_xor(s, 4);
            s += __shfl_xor(s, 8);
            if (cc == 0) part[wc * 128 + wr * 64 + mt * 16 + qg * 4 + r] = s;
        }
    }
    __syncthreads();
    if (tid < 128) {
        float sc = part[tid] + part[128 + tid];
        scores[(size_t)b * S_ + s0 + tid] = sc;
        sarr[tid] = sc;
    }
    __syncthreads();
    // local max over 128 scores (wave 0)
    if (tid < 64) {
        float m = fmaxf(sarr[tid], sarr[tid + 64]);
#pragma unroll
        for (int off = 32; off >= 1; off >>= 1) m = fmaxf(m, __shfl_xor(m, off));
        if (tid == 0) redm[0] = m;
    }
    __syncthreads();
    float M = redm[0];
    if (tid < 128) parr[tid] = __expf(sarr[tid] - M);
    __syncthreads();
    if (tid < 64) {
        float l = parr[tid] + parr[tid + 64];
#pragma unroll
        for (int off = 32; off >= 1; off >>= 1) l += __shfl_xor(l, off);
        if (tid == 0) { mbuf[b * NCHUNK + cid] = M; lbuf[b * NCHUNK + cid] = l; }
    }

    // partial context: ctx_part[d] = sum_{r=0..127} p[r] * values[s0+r][d]
    // tile was just read -> L2/L3-hot (values fits in the 256 MiB L3)
    int g = tid & 63, sub = tid >> 6;
    floatx4 acc4 = {0.f, 0.f, 0.f, 0.f};
#pragma unroll 4
    for (int i = 0; i < 32; ++i) {
        int r = i * 4 + sub;
        float w = parr[r];
        floatx4 v = *reinterpret_cast<const floatx4*>(vb + (size_t)r * D_ + g * 4);
        acc4 += v * w;
    }
    cbuf[tid] = acc4;
    __syncthreads();
    if (tid < 64) {
        floatx4 r4 = cbuf[tid] + cbuf[tid + 64] + cbuf[tid + 128] + cbuf[tid + 192];
        *reinterpret_cast<floatx4*>(cpart + ((size_t)b * NCHUNK + cid) * D_ + g * 4) = r4;
    }
}

// Kernel 3: merge chunk stats -> M,Z; write weights + combined context.
__global__ __launch_bounds__(256) void finalize_kernel(
        const float* __restrict__ scores, const float* __restrict__ mbuf,
        const float* __restrict__ lbuf, const float* __restrict__ cpart,
        float* __restrict__ out) {
    int b = blockIdx.x;
    int tid = threadIdx.x;
    __shared__ float alpha[NCHUNK];
    __shared__ float MZ[2];
    if (tid < 64) {
        float m = mbuf[b * NCHUNK + tid];
        float l = lbuf[b * NCHUNK + tid];
        float M = m;
#pragma unroll
        for (int off = 32; off >= 1; off >>= 1) M = fmaxf(M, __shfl_xor(M, off));
        float z = l * __expf(m - M);
#pragma unroll
        for (int off = 32; off >= 1; off >>= 1) z += __shfl_xor(z, off);
        if (tid == 0) { MZ[0] = M; MZ[1] = z; }
    }
    __syncthreads();
    float M = MZ[0];
    float invZ = 1.f / MZ[1];
    if (tid < 64) alpha[tid] = __expf(mbuf[b * NCHUNK + tid] - M) * invZ;
    __syncthreads();

    // weights
    const floatx4* sc4 = reinterpret_cast<const floatx4*>(scores + (size_t)b * S_);
    floatx4* w4 = reinterpret_cast<floatx4*>(out + B_ * D_ + (size_t)b * S_);
#pragma unroll
    for (int i = 0; i < 8; ++i) {
        floatx4 v = sc4[tid + i * 256];
        floatx4 w;
#pragma unroll
        for (int j = 0; j < 4; ++j) w[j] = __expf(v[j] - M) * invZ;
        w4[tid + i * 256] = w;
    }

    // context: out[b][d] = sum_c alpha_c * cpart[b][c][d]
    float acc = 0.f;
#pragma unroll 8
    for (int c = 0; c < NCHUNK; ++c)
        acc = fmaf(alpha[c], cpart[((size_t)b * NCHUNK + c) * D_ + tid], acc);
    out[b * D_ + tid] = acc;
}

extern "C" void kernel_launch(void* const* d_in, const int* in_sizes, int n_in,
                              void* d_out, int out_size, void* d_ws, size_t ws_size,
                              hipStream_t stream) {
    const float* query  = (const float*)d_in[0];
    const float* values = (const float*)d_in[1];
    const float* W1     = (const float*)d_in[2];
    const float* W2     = (const float*)d_in[3];
    const float* V      = (const float*)d_in[4];
    float* out = (float*)d_out;

    char* ws = (char*)d_ws;
    unsigned short* w1t = (unsigned short*)ws;               ws += 65536;      // 64 KiB
    float* pq     = (float*)ws;                              ws += 16384;      // 16 KiB
    float* scores = (float*)ws;                              ws += B_ * S_ * 4;       // 1 MiB
    float* mbuf   = (float*)ws;                              ws += B_ * NCHUNK * 4;   // 8 KiB
    float* lbuf   = (float*)ws;                              ws += B_ * NCHUNK * 4;   // 8 KiB
    float* cpart  = (float*)ws;                                             // 2 MiB

    prep_kernel<<<dim3(32), dim3(128), 0, stream>>>(query, W1, W2, pq, w1t);
    fused_kernel<<<dim3(NCHUNK, B_), dim3(256), 0, stream>>>(values, w1t, pq, V,
                                                             scores, mbuf, lbuf, cpart);
    finalize_kernel<<<dim3(B_), dim3(256), 0, stream>>>(scores, mbuf, lbuf, cpart, out);
}

// Round 3
// 419.335 us; speedup vs baseline: 1.0704x; 1.0219x over previous
//
#include <hip/hip_runtime.h>
#include <stdint.h>

#define B_ 32
#define S_ 8192
#define D_ 256
#define Q_ 256
#define U_ 128
#define NCHUNK 64   // S_/128 chunks per batch
#define LSTR 72     // LDS row stride in ushorts (64 data + 8 pad; 16B-aligned rows)

typedef float floatx4 __attribute__((ext_vector_type(4)));
typedef float f32x4 __attribute__((ext_vector_type(4)));
typedef __bf16 bf16x8 __attribute__((ext_vector_type(8)));
typedef unsigned short ushortx4 __attribute__((ext_vector_type(4)));
typedef unsigned short ushortx8 __attribute__((ext_vector_type(8)));

static __device__ __forceinline__ unsigned short f2bf(float f) {
    unsigned int x = __builtin_bit_cast(unsigned int, f);
    x += 0x7FFFu + ((x >> 16) & 1u);   // RNE (inputs are finite/normal)
    return (unsigned short)(x >> 16);
}

static __device__ __forceinline__ float fast_tanh(float x) {
    x = fminf(15.f, fmaxf(-15.f, x));
    float e = __expf(2.f * x);
    return __fdividef(e - 1.f, e + 1.f);
}

// Kernel 1: proj_q[b][u] = sum_q query[b][q]*W2[q][u]; also W1^T -> bf16 in ws.
__global__ __launch_bounds__(128) void prep_kernel(
        const float* __restrict__ query, const float* __restrict__ W1,
        const float* __restrict__ W2, float* __restrict__ pq,
        unsigned short* __restrict__ w1t) {
    int b = blockIdx.x;
    int t = threadIdx.x;  // 0..127
    __shared__ float qrow[Q_];
    qrow[t] = query[b * Q_ + t];
    qrow[t + 128] = query[b * Q_ + 128 + t];
    __syncthreads();
    float acc = 0.f;
#pragma unroll 8
    for (int q = 0; q < Q_; ++q) acc = fmaf(qrow[q], W2[q * U_ + t], acc);
    pq[b * U_ + t] = acc;
    int base = (b * 128 + t) * 8;
#pragma unroll
    for (int j = 0; j < 8; ++j) {
        int e = base + j;
        int n = e >> 8, k = e & 255;
        w1t[e] = f2bf(W1[k * U_ + n]);
    }
}

// Kernel 2 (fused): per (b, 128-row chunk):
//   scores via MFMA (BK=64, 4 k-iters) -> raw scores to ws; local max m,
//   p=exp(s-m), sum l; partial context sum_s p_s*values[s,:] (L2-hot re-read).
__global__ __launch_bounds__(256, 4) void fused_kernel(
        const float* __restrict__ values, const unsigned short* __restrict__ w1t,
        const float* __restrict__ pq, const float* __restrict__ V,
        float* __restrict__ scores, float* __restrict__ mbuf,
        float* __restrict__ lbuf, float* __restrict__ cpart) {
    // 2 x 128 x LSTR ushorts = 36 KiB total; epilogue buffers alias As.
    __shared__ __align__(16) char smem[2 * 128 * LSTR * 2];
    unsigned short* As = (unsigned short*)smem;
    unsigned short* Bs = As + 128 * LSTR;
    float* part = (float*)smem;                 // 256 f  [0,1024)
    float* sarr = part + 256;                   // 128 f  [1024,1536)
    float* parr = sarr + 128;                   // 128 f  [1536,2048)
    float* redm = parr + 128;                   // 1 f
    floatx4* cbuf = (floatx4*)(smem + 4096);    // 256 f4 [4096,8192)

    int b = blockIdx.y;
    int cid = blockIdx.x;
    int s0 = cid * 128;
    int tid = threadIdx.x;
    int lane = tid & 63;
    int wave = tid >> 6;
    int wr = wave >> 1, wc = wave & 1;
    int cc = lane & 15, qg = lane >> 4;

    const float* vb = values + ((size_t)b * S_ + s0) * D_;

    f32x4 acc[4][4];
#pragma unroll
    for (int mt = 0; mt < 4; ++mt)
#pragma unroll
        for (int nt = 0; nt < 4; ++nt) acc[mt][nt] = (f32x4){0.f, 0.f, 0.f, 0.f};

    // A staging: 128 rows x 16 chunks(16B) ; idx = tid + i*256, i<8
    int arow = tid >> 4, ac = tid & 15;         // +i*16 rows per i
    // B staging: 128 rows x 8 chunks(16B) ; idx = tid + i*256, i<4
    int brow = tid >> 3, bc = tid & 7;          // +i*32 rows per i

    for (int kt = 0; kt < 4; ++kt) {
        int k0 = kt * 64;
        __syncthreads();
#pragma unroll
        for (int i = 0; i < 8; ++i) {
            int row = arow + i * 16;
            floatx4 v = *reinterpret_cast<const floatx4*>(vb + (size_t)row * D_ + k0 + ac * 4);
            ushortx4 u;
            u[0] = f2bf(v[0]); u[1] = f2bf(v[1]); u[2] = f2bf(v[2]); u[3] = f2bf(v[3]);
            *reinterpret_cast<ushortx4*>(&As[row * LSTR + ac * 4]) = u;
        }
#pragma unroll
        for (int i = 0; i < 4; ++i) {
            int row = brow + i * 32;
            ushortx8 w = *reinterpret_cast<const ushortx8*>(&w1t[row * 256 + k0 + bc * 8]);
            *reinterpret_cast<ushortx8*>(&Bs[row * LSTR + bc * 8]) = w;
        }
        __syncthreads();
#pragma unroll
        for (int ks = 0; ks < 2; ++ks) {
            bf16x8 af[4], bfr[4];
#pragma unroll
            for (int mt = 0; mt < 4; ++mt)
                af[mt] = *reinterpret_cast<const bf16x8*>(
                    &As[(wr * 64 + mt * 16 + cc) * LSTR + ks * 32 + qg * 8]);
#pragma unroll
            for (int nt = 0; nt < 4; ++nt)
                bfr[nt] = *reinterpret_cast<const bf16x8*>(
                    &Bs[(wc * 64 + nt * 16 + cc) * LSTR + ks * 32 + qg * 8]);
#pragma unroll
            for (int mt = 0; mt < 4; ++mt)
#pragma unroll
                for (int nt = 0; nt < 4; ++nt)
                    acc[mt][nt] = __builtin_amdgcn_mfma_f32_16x16x32_bf16(
                        af[mt], bfr[nt], acc[mt][nt], 0, 0, 0);
        }
    }
    __syncthreads();   // all waves done reading As/Bs; safe to alias

    // tanh + dot-V epilogue -> per-row score partials
    float Vu[4], pqu[4];
#pragma unroll
    for (int nt = 0; nt < 4; ++nt) {
        int u = wc * 64 + nt * 16 + cc;
        Vu[nt] = V[u];
        pqu[nt] = pq[b * U_ + u];
    }
#pragma unroll
    for (int mt = 0; mt < 4; ++mt) {
#pragma unroll
        for (int r = 0; r < 4; ++r) {
            float s = 0.f;
#pragma unroll
            for (int nt = 0; nt < 4; ++nt)
                s += Vu[nt] * fast_tanh(acc[mt][nt][r] + pqu[nt]);
            s += __shfl_xor(s, 1);
            s += __shfl_xor(s, 2);
            s += __shfl_xor(s, 4);
            s += __shfl_xor(s, 8);
            if (cc == 0) part[wc * 128 + wr * 64 + mt * 16 + qg * 4 + r] = s;
        }
    }
    __syncthreads();
    if (tid < 128) {
        float sc = part[tid] + part[128 + tid];
        scores[(size_t)b * S_ + s0 + tid] = sc;
        sarr[tid] = sc;
    }
    __syncthreads();
    if (tid < 64) {
        float m = fmaxf(sarr[tid], sarr[tid + 64]);
#pragma unroll
        for (int off = 32; off >= 1; off >>= 1) m = fmaxf(m, __shfl_xor(m, off));
        if (tid == 0) redm[0] = m;
    }
    __syncthreads();
    float M = redm[0];
    if (tid < 128) parr[tid] = __expf(sarr[tid] - M);
    __syncthreads();
    if (tid < 64) {
        float l = parr[tid] + parr[tid + 64];
#pragma unroll
        for (int off = 32; off >= 1; off >>= 1) l += __shfl_xor(l, off);
        if (tid == 0) { mbuf[b * NCHUNK + cid] = M; lbuf[b * NCHUNK + cid] = l; }
    }

    // partial context (tile is L2-hot from the MFMA staging pass)
    int g = tid & 63, sub = tid >> 6;
    floatx4 acc4 = {0.f, 0.f, 0.f, 0.f};
#pragma unroll 4
    for (int i = 0; i < 32; ++i) {
        int r = i * 4 + sub;
        float w = parr[r];
        floatx4 v = *reinterpret_cast<const floatx4*>(vb + (size_t)r * D_ + g * 4);
        acc4 += v * w;
    }
    cbuf[tid] = acc4;
    __syncthreads();
    if (tid < 64) {
        floatx4 r4 = cbuf[tid] + cbuf[tid + 64] + cbuf[tid + 128] + cbuf[tid + 192];
        *reinterpret_cast<floatx4*>(cpart + ((size_t)b * NCHUNK + cid) * D_ + g * 4) = r4;
    }
}

// Kernel 3: grid (B_, 9). y<8: write 1024 weights; y==8: combined context.
// Each block recomputes M,Z from mbuf/lbuf (64 floats, trivial).
__global__ __launch_bounds__(256) void finalize_kernel(
        const float* __restrict__ scores, const float* __restrict__ mbuf,
        const float* __restrict__ lbuf, const float* __restrict__ cpart,
        float* __restrict__ out) {
    int b = blockIdx.x;
    int part_id = blockIdx.y;
    int tid = threadIdx.x;
    __shared__ float MZ[2];
    __shared__ float alpha[NCHUNK];
    if (tid < 64) {
        float m = mbuf[b * NCHUNK + tid];
        float l = lbuf[b * NCHUNK + tid];
        float M = m;
#pragma unroll
        for (int off = 32; off >= 1; off >>= 1) M = fmaxf(M, __shfl_xor(M, off));
        float z = l * __expf(m - M);
#pragma unroll
        for (int off = 32; off >= 1; off >>= 1) z += __shfl_xor(z, off);
        if (tid == 0) { MZ[0] = M; MZ[1] = z; }
    }
    __syncthreads();
    float M = MZ[0];
    float invZ = 1.f / MZ[1];

    if (part_id < 8) {
        // weights slice: 1024 scores -> out[B_*D_ + b*S_ + part_id*1024 ...]
        size_t off = (size_t)b * S_ + part_id * 1024;
        floatx4 v = *reinterpret_cast<const floatx4*>(scores + off + tid * 4);
        floatx4 w;
#pragma unroll
        for (int j = 0; j < 4; ++j) w[j] = __expf(v[j] - M) * invZ;
        *reinterpret_cast<floatx4*>(out + B_ * D_ + off + tid * 4) = w;
    } else {
        if (tid < 64) alpha[tid] = __expf(mbuf[b * NCHUNK + tid] - M) * invZ;
        __syncthreads();
        float acc = 0.f;
#pragma unroll 8
        for (int c = 0; c < NCHUNK; ++c)
            acc = fmaf(alpha[c], cpart[((size_t)b * NCHUNK + c) * D_ + tid], acc);
        out[b * D_ + tid] = acc;
    }
}

extern "C" void kernel_launch(void* const* d_in, const int* in_sizes, int n_in,
                              void* d_out, int out_size, void* d_ws, size_t ws_size,
                              hipStream_t stream) {
    const float* query  = (const float*)d_in[0];
    const float* values = (const float*)d_in[1];
    const float* W1     = (const float*)d_in[2];
    const float* W2     = (const float*)d_in[3];
    const float* V      = (const float*)d_in[4];
    float* out = (float*)d_out;

    char* ws = (char*)d_ws;
    unsigned short* w1t = (unsigned short*)ws;               ws += 65536;           // 64 KiB
    float* pq     = (float*)ws;                              ws += 16384;           // 16 KiB
    float* scores = (float*)ws;                              ws += B_ * S_ * 4;     // 1 MiB
    float* mbuf   = (float*)ws;                              ws += B_ * NCHUNK * 4; // 8 KiB
    float* lbuf   = (float*)ws;                              ws += B_ * NCHUNK * 4; // 8 KiB
    float* cpart  = (float*)ws;                                                    // 2 MiB

    prep_kernel<<<dim3(32), dim3(128), 0, stream>>>(query, W1, W2, pq, w1t);
    fused_kernel<<<dim3(NCHUNK, B_), dim3(256), 0, stream>>>(values, w1t, pq, V,
                                                             scores, mbuf, lbuf, cpart);
    finalize_kernel<<<dim3(B_, 9), dim3(256), 0, stream>>>(scores, mbuf, lbuf, cpart, out);
}

// Round 4
// 417.254 us; speedup vs baseline: 1.0757x; 1.0050x over previous
//
#include <hip/hip_runtime.h>
#include <stdint.h>

#define B_ 32
#define S_ 8192
#define D_ 256
#define Q_ 256
#define U_ 128
#define NCHUNK 64   // S_/128 chunks per batch

typedef float floatx4 __attribute__((ext_vector_type(4)));
typedef float f32x4 __attribute__((ext_vector_type(4)));
typedef __bf16 bf16x8 __attribute__((ext_vector_type(8)));
typedef unsigned short ushortx4 __attribute__((ext_vector_type(4)));
typedef unsigned short ushortx8 __attribute__((ext_vector_type(8)));

static __device__ __forceinline__ unsigned short f2bf(float f) {
    unsigned int x = __builtin_bit_cast(unsigned int, f);
    x += 0x7FFFu + ((x >> 16) & 1u);   // RNE (inputs are finite/normal)
    return (unsigned short)(x >> 16);
}

static __device__ __forceinline__ float bf2f(unsigned short u) {
    unsigned int x = ((unsigned int)u) << 16;
    return __builtin_bit_cast(float, x);
}

static __device__ __forceinline__ float fast_tanh(float x) {
    x = fminf(15.f, fmaxf(-15.f, x));
    float e = __expf(2.f * x);
    return __fdividef(e - 1.f, e + 1.f);
}

// Kernel 1: proj_q[b][u] = sum_q query[b][q]*W2[q][u]; also W1^T -> bf16 in ws.
__global__ __launch_bounds__(128) void prep_kernel(
        const float* __restrict__ query, const float* __restrict__ W1,
        const float* __restrict__ W2, float* __restrict__ pq,
        unsigned short* __restrict__ w1t) {
    int b = blockIdx.x;
    int t = threadIdx.x;  // 0..127
    __shared__ float qrow[Q_];
    qrow[t] = query[b * Q_ + t];
    qrow[t + 128] = query[b * Q_ + 128 + t];
    __syncthreads();
    float acc = 0.f;
#pragma unroll 8
    for (int q = 0; q < Q_; ++q) acc = fmaf(qrow[q], W2[q * U_ + t], acc);
    pq[b * U_ + t] = acc;
    int base = (b * 128 + t) * 8;
#pragma unroll
    for (int j = 0; j < 8; ++j) {
        int e = base + j;
        int n = e >> 8, k = e & 255;
        w1t[e] = f2bf(W1[k * U_ + n]);
    }
}

// Kernel 2 (fused): per (b, 128-row chunk):
//   Full 128x256 bf16 A-tile in LDS (XOR-swizzled, 64 KiB). Bs = per-kt
//   128x64 bf16 slice (16 KiB) restaged from L2-resident w1t.  80 KiB total
//   -> 2 blocks/CU.  Scores via MFMA -> ws; local softmax stats; partial
//   context computed FROM LDS bf16 (no global re-read -> single HBM pass).
__global__ __launch_bounds__(256, 2) void fused_kernel(
        const float* __restrict__ values, const unsigned short* __restrict__ w1t,
        const float* __restrict__ pq, const float* __restrict__ V,
        float* __restrict__ scores, float* __restrict__ mbuf,
        float* __restrict__ lbuf, float* __restrict__ cpart) {
    __shared__ __align__(16) char smem[81920];
    unsigned short* As = (unsigned short*)smem;            // 128 x 256 ushorts, 16B-chunk swizzle
    unsigned short* Bs = (unsigned short*)(smem + 65536);  // 128 x 64 ushorts, swizzled
    // epilogue buffers alias the Bs region (Bs dead after last MFMA barrier)
    float* part = (float*)(smem + 65536);                  // 256 f
    float* sarr = part + 256;                              // 128 f
    float* parr = sarr + 128;                              // 128 f
    float* redm = parr + 128;                              // 1 f
    floatx4* cbuf = (floatx4*)(smem + 65536 + 4096);       // 256 f4

    int b = blockIdx.y;
    int cid = blockIdx.x;
    int s0 = cid * 128;
    int tid = threadIdx.x;
    int lane = tid & 63;
    int wave = tid >> 6;
    int wr = wave >> 1, wc = wave & 1;
    int cc = lane & 15, qg = lane >> 4;
    int cc7 = cc & 7;

    const float* vb = values + ((size_t)b * S_ + s0) * D_;

    f32x4 acc[4][4];
#pragma unroll
    for (int mt = 0; mt < 4; ++mt)
#pragma unroll
        for (int nt = 0; nt < 4; ++nt) acc[mt][nt] = (f32x4){0.f, 0.f, 0.f, 0.f};

    // ---- Stage full A tile: 8192 float4 chunks, 32 per thread.
    // Per wave+i: one row, 64 lanes cover its 1 KiB contiguously (perfect coalesce).
#pragma unroll
    for (int i = 0; i < 32; ++i) {
        int fidx = tid + i * 256;
        int row = fidx >> 6, fc = fidx & 63;
        floatx4 v = *reinterpret_cast<const floatx4*>(vb + (size_t)row * D_ + fc * 4);
        ushortx4 u;
        u[0] = f2bf(v[0]); u[1] = f2bf(v[1]); u[2] = f2bf(v[2]); u[3] = f2bf(v[3]);
        int addr = row * 256 + (((fc >> 1) ^ (row & 7)) << 3) + (fc & 1) * 4;
        *reinterpret_cast<ushortx4*>(&As[addr]) = u;
    }
    // ---- Stage B slice kt=0 (1024 16B chunks, 4 per thread; from L2-hot w1t)
#pragma unroll
    for (int i = 0; i < 4; ++i) {
        int cidx = tid + i * 256;
        int n = cidx >> 3, kc = cidx & 7;
        ushortx8 w = *reinterpret_cast<const ushortx8*>(&w1t[n * 256 + kc * 8]);
        *reinterpret_cast<ushortx8*>(&Bs[n * 64 + ((kc ^ (n & 7)) << 3)]) = w;
    }
    __syncthreads();

    for (int kt = 0; kt < 4; ++kt) {
#pragma unroll
        for (int ks = 0; ks < 2; ++ks) {
            int ksg = kt * 2 + ks;
            bf16x8 af[4], bfr[4];
#pragma unroll
            for (int mt = 0; mt < 4; ++mt) {
                int r = wr * 64 + mt * 16 + cc;
                af[mt] = *reinterpret_cast<const bf16x8*>(
                    &As[r * 256 + (((ksg * 4 + qg) ^ cc7) << 3)]);
            }
#pragma unroll
            for (int nt = 0; nt < 4; ++nt) {
                int n = wc * 64 + nt * 16 + cc;
                bfr[nt] = *reinterpret_cast<const bf16x8*>(
                    &Bs[n * 64 + (((ks * 4 + qg) ^ cc7) << 3)]);
            }
#pragma unroll
            for (int mt = 0; mt < 4; ++mt)
#pragma unroll
                for (int nt = 0; nt < 4; ++nt)
                    acc[mt][nt] = __builtin_amdgcn_mfma_f32_16x16x32_bf16(
                        af[mt], bfr[nt], acc[mt][nt], 0, 0, 0);
        }
        __syncthreads();   // all waves done reading this Bs slice
        if (kt < 3) {
            int kt1 = kt + 1;
#pragma unroll
            for (int i = 0; i < 4; ++i) {
                int cidx = tid + i * 256;
                int n = cidx >> 3, kc = cidx & 7;
                ushortx8 w = *reinterpret_cast<const ushortx8*>(
                    &w1t[n * 256 + kt1 * 64 + kc * 8]);
                *reinterpret_cast<ushortx8*>(&Bs[n * 64 + ((kc ^ (n & 7)) << 3)]) = w;
            }
            __syncthreads();
        }
    }
    // Bs region now dead -> epilogue buffers alias it.

    // tanh + dot-V epilogue -> per-row score partials
    float Vu[4], pqu[4];
#pragma unroll
    for (int nt = 0; nt < 4; ++nt) {
        int u = wc * 64 + nt * 16 + cc;
        Vu[nt] = V[u];
        pqu[nt] = pq[b * U_ + u];
    }
#pragma unroll
    for (int mt = 0; mt < 4; ++mt) {
#pragma unroll
        for (int r = 0; r < 4; ++r) {
            float s = 0.f;
#pragma unroll
            for (int nt = 0; nt < 4; ++nt)
                s += Vu[nt] * fast_tanh(acc[mt][nt][r] + pqu[nt]);
            s += __shfl_xor(s, 1);
            s += __shfl_xor(s, 2);
            s += __shfl_xor(s, 4);
            s += __shfl_xor(s, 8);
            if (cc == 0) part[wc * 128 + wr * 64 + mt * 16 + qg * 4 + r] = s;
        }
    }
    __syncthreads();
    if (tid < 128) {
        float sc = part[tid] + part[128 + tid];
        scores[(size_t)b * S_ + s0 + tid] = sc;
        sarr[tid] = sc;
    }
    __syncthreads();
    if (tid < 64) {
        float m = fmaxf(sarr[tid], sarr[tid + 64]);
#pragma unroll
        for (int off = 32; off >= 1; off >>= 1) m = fmaxf(m, __shfl_xor(m, off));
        if (tid == 0) redm[0] = m;
    }
    __syncthreads();
    float M = redm[0];
    if (tid < 128) parr[tid] = __expf(sarr[tid] - M);
    __syncthreads();
    if (tid < 64) {
        float l = parr[tid] + parr[tid + 64];
#pragma unroll
        for (int off = 32; off >= 1; off >>= 1) l += __shfl_xor(l, off);
        if (tid == 0) { mbuf[b * NCHUNK + cid] = M; lbuf[b * NCHUNK + cid] = l; }
    }
    __syncthreads();

    // partial context from the LDS bf16 tile (no global re-read).
    // wave-uniform row r; 64 lanes cover the row's 64 8B-slots -> conflict-free.
    int g = tid & 63, sub = tid >> 6;
    floatx4 acc4 = {0.f, 0.f, 0.f, 0.f};
#pragma unroll 4
    for (int i = 0; i < 32; ++i) {
        int r = i * 4 + sub;
        float w = parr[r];
        int addr = r * 256 + (((g >> 1) ^ (r & 7)) << 3) + (g & 1) * 4;
        ushortx4 u = *reinterpret_cast<const ushortx4*>(&As[addr]);
        acc4[0] = fmaf(bf2f(u[0]), w, acc4[0]);
        acc4[1] = fmaf(bf2f(u[1]), w, acc4[1]);
        acc4[2] = fmaf(bf2f(u[2]), w, acc4[2]);
        acc4[3] = fmaf(bf2f(u[3]), w, acc4[3]);
    }
    cbuf[tid] = acc4;
    __syncthreads();
    if (tid < 64) {
        floatx4 r4 = cbuf[tid] + cbuf[tid + 64] + cbuf[tid + 128] + cbuf[tid + 192];
        *reinterpret_cast<floatx4*>(cpart + ((size_t)b * NCHUNK + cid) * D_ + g * 4) = r4;
    }
}

// Kernel 3: grid (B_, 9). y<8: write 1024 weights; y==8: combined context.
__global__ __launch_bounds__(256) void finalize_kernel(
        const float* __restrict__ scores, const float* __restrict__ mbuf,
        const float* __restrict__ lbuf, const float* __restrict__ cpart,
        float* __restrict__ out) {
    int b = blockIdx.x;
    int part_id = blockIdx.y;
    int tid = threadIdx.x;
    __shared__ float MZ[2];
    __shared__ float alpha[NCHUNK];
    if (tid < 64) {
        float m = mbuf[b * NCHUNK + tid];
        float l = lbuf[b * NCHUNK + tid];
        float M = m;
#pragma unroll
        for (int off = 32; off >= 1; off >>= 1) M = fmaxf(M, __shfl_xor(M, off));
        float z = l * __expf(m - M);
#pragma unroll
        for (int off = 32; off >= 1; off >>= 1) z += __shfl_xor(z, off);
        if (tid == 0) { MZ[0] = M; MZ[1] = z; }
    }
    __syncthreads();
    float M = MZ[0];
    float invZ = 1.f / MZ[1];

    if (part_id < 8) {
        size_t off = (size_t)b * S_ + part_id * 1024;
        floatx4 v = *reinterpret_cast<const floatx4*>(scores + off + tid * 4);
        floatx4 w;
#pragma unroll
        for (int j = 0; j < 4; ++j) w[j] = __expf(v[j] - M) * invZ;
        *reinterpret_cast<floatx4*>(out + B_ * D_ + off + tid * 4) = w;
    } else {
        if (tid < 64) alpha[tid] = __expf(mbuf[b * NCHUNK + tid] - M) * invZ;
        __syncthreads();
        float acc = 0.f;
#pragma unroll 8
        for (int c = 0; c < NCHUNK; ++c)
            acc = fmaf(alpha[c], cpart[((size_t)b * NCHUNK + c) * D_ + tid], acc);
        out[b * D_ + tid] = acc;
    }
}

extern "C" void kernel_launch(void* const* d_in, const int* in_sizes, int n_in,
                              void* d_out, int out_size, void* d_ws, size_t ws_size,
                              hipStream_t stream) {
    const float* query  = (const float*)d_in[0];
    const float* values = (const float*)d_in[1];
    const float* W1     = (const float*)d_in[2];
    const float* W2     = (const float*)d_in[3];
    const float* V      = (const float*)d_in[4];
    float* out = (float*)d_out;

    char* ws = (char*)d_ws;
    unsigned short* w1t = (unsigned short*)ws;               ws += 65536;           // 64 KiB
    float* pq     = (float*)ws;                              ws += 16384;           // 16 KiB
    float* scores = (float*)ws;                              ws += B_ * S_ * 4;     // 1 MiB
    float* mbuf   = (float*)ws;                              ws += B_ * NCHUNK * 4; // 8 KiB
    float* lbuf   = (float*)ws;                              ws += B_ * NCHUNK * 4; // 8 KiB
    float* cpart  = (float*)ws;                                                    // 2 MiB

    prep_kernel<<<dim3(32), dim3(128), 0, stream>>>(query, W1, W2, pq, w1t);
    fused_kernel<<<dim3(NCHUNK, B_), dim3(256), 0, stream>>>(values, w1t, pq, V,
                                                             scores, mbuf, lbuf, cpart);
    finalize_kernel<<<dim3(B_, 9), dim3(256), 0, stream>>>(scores, mbuf, lbuf, cpart, out);
}

// Round 5
// 391.267 us; speedup vs baseline: 1.1472x; 1.0664x over previous
//
#include <hip/hip_runtime.h>
#include <stdint.h>

#define B_ 32
#define S_ 8192
#define D_ 256
#define Q_ 256
#define U_ 128
#define NCHUNK 128   // S_/64 chunks per batch (M=64 rows per block)

typedef float floatx4 __attribute__((ext_vector_type(4)));
typedef float f32x4 __attribute__((ext_vector_type(4)));
typedef __bf16 bf16x8 __attribute__((ext_vector_type(8)));
typedef unsigned short ushortx4 __attribute__((ext_vector_type(4)));
typedef unsigned short ushortx8 __attribute__((ext_vector_type(8)));

static __device__ __forceinline__ unsigned short f2bf(float f) {
    unsigned int x = __builtin_bit_cast(unsigned int, f);
    x += 0x7FFFu + ((x >> 16) & 1u);   // RNE (inputs are finite/normal)
    return (unsigned short)(x >> 16);
}

static __device__ __forceinline__ float bf2f(unsigned short u) {
    unsigned int x = ((unsigned int)u) << 16;
    return __builtin_bit_cast(float, x);
}

static __device__ __forceinline__ float fast_tanh(float x) {
    x = fminf(15.f, fmaxf(-15.f, x));
    float e = __expf(2.f * x);
    return __fdividef(e - 1.f, e + 1.f);
}

// Kernel 1: proj_q[b][u] = sum_q query[b][q]*W2[q][u]; W1^T -> bf16 in ws,
// stored kt-major: element (n,k) at (k>>6)*8192 + n*64 + (k&63)  (16-KiB slices).
__global__ __launch_bounds__(128) void prep_kernel(
        const float* __restrict__ query, const float* __restrict__ W1,
        const float* __restrict__ W2, float* __restrict__ pq,
        unsigned short* __restrict__ w1t) {
    int b = blockIdx.x;
    int t = threadIdx.x;  // 0..127
    __shared__ float qrow[Q_];
    qrow[t] = query[b * Q_ + t];
    qrow[t + 128] = query[b * Q_ + 128 + t];
    __syncthreads();
    float acc = 0.f;
#pragma unroll 8
    for (int q = 0; q < Q_; ++q) acc = fmaf(qrow[q], W2[q * U_ + t], acc);
    pq[b * U_ + t] = acc;
    int base = (b * 128 + t) * 8;
#pragma unroll
    for (int j = 0; j < 8; ++j) {
        int e = base + j;
        int n = e >> 8, k = e & 255;
        w1t[(k >> 6) * 8192 + n * 64 + (k & 63)] = f2bf(W1[k * U_ + n]);
    }
}

// Kernel 2 (fused): per (b, 64-row chunk):
//   A tile 64x256 bf16 in LDS (32 KiB, XOR swizzle), staged in 4 K-slices
//   software-pipelined against MFMA (loads in flight across the barrier).
//   Bs = per-kt 128x64 slice (16 KiB) from kt-major w1t (L2-hot, contiguous).
//   48 KiB LDS -> 3 blocks/CU. Scores -> ws; local softmax stats; partial
//   context from LDS bf16 (single HBM pass over values).
__global__ __launch_bounds__(256, 3) void fused_kernel(
        const float* __restrict__ values, const unsigned short* __restrict__ w1t,
        const float* __restrict__ pq, const float* __restrict__ V,
        float* __restrict__ scores, float* __restrict__ mbuf,
        float* __restrict__ lbuf, float* __restrict__ cpart) {
    __shared__ __align__(16) char smem[49152];
    unsigned short* As = (unsigned short*)smem;            // 64 x 256 ushorts, swizzled
    unsigned short* Bs = (unsigned short*)(smem + 32768);  // 128 x 64 ushorts, swizzled
    // epilogue buffers alias Bs (dead after final MFMA barrier)
    float* part = (float*)(smem + 32768);                  // 128 f
    float* sarr = part + 128;                              // 64 f
    float* parr = sarr + 64;                               // 64 f
    float* redm = parr + 64;                               // 1 f
    floatx4* cbuf = (floatx4*)(smem + 32768 + 4096);       // 256 f4

    int b = blockIdx.y;
    int cid = blockIdx.x;
    int s0 = cid * 64;
    int tid = threadIdx.x;
    int lane = tid & 63;
    int wave = tid >> 6;
    int wr = wave >> 1, wc = wave & 1;
    int cc = lane & 15, qg = lane >> 4;
    int cc7 = cc & 7;

    const float* vb = values + ((size_t)b * S_ + s0) * D_;

    f32x4 acc[2][4];
#pragma unroll
    for (int mt = 0; mt < 2; ++mt)
#pragma unroll
        for (int nt = 0; nt < 4; ++nt) acc[mt][nt] = (f32x4){0.f, 0.f, 0.f, 0.f};

    floatx4 areg[4];
    ushortx8 breg[4];
    // staging index decode (constant per thread):
    //  A: fidx = tid + i*256 -> row = fidx>>4 (64 rows), fc = fidx&15 (16 float4/row-slice)
    //  B: cidx = tid + i*256 -> n = cidx>>3 (128 n), kc = cidx&7 (8 16B-chunks/n-slice)
    int arow = tid >> 4, afc = tid & 15;
    int bn = tid >> 3, bkc = tid & 7;

    auto load_a = [&](int kt) {
#pragma unroll
        for (int i = 0; i < 4; ++i) {
            int row = arow + i * 16;
            areg[i] = *reinterpret_cast<const floatx4*>(vb + (size_t)row * D_ + kt * 64 + afc * 4);
        }
    };
    auto load_b = [&](int kt) {
#pragma unroll
        for (int i = 0; i < 4; ++i) {
            int cidx = tid + i * 256;
            breg[i] = *reinterpret_cast<const ushortx8*>(&w1t[kt * 8192 + cidx * 8]);
        }
    };
    auto write_ab = [&](int kt) {
#pragma unroll
        for (int i = 0; i < 4; ++i) {
            int row = arow + i * 16;
            ushortx4 u;
            u[0] = f2bf(areg[i][0]); u[1] = f2bf(areg[i][1]);
            u[2] = f2bf(areg[i][2]); u[3] = f2bf(areg[i][3]);
            int chunk16 = kt * 8 + (afc >> 1);
            int addr = row * 256 + ((chunk16 ^ (row & 7)) << 3) + (afc & 1) * 4;
            *reinterpret_cast<ushortx4*>(&As[addr]) = u;
        }
#pragma unroll
        for (int i = 0; i < 4; ++i) {
            int n = bn + i * 32;
            *reinterpret_cast<ushortx8*>(&Bs[n * 64 + ((bkc ^ (n & 7)) << 3)]) = breg[i];
        }
    };

    load_a(0); load_b(0);
    write_ab(0);
    load_a(1); load_b(1);          // in flight across first MFMA block
    __syncthreads();

#pragma unroll
    for (int kt = 0; kt < 4; ++kt) {
#pragma unroll
        for (int ks = 0; ks < 2; ++ks) {
            int ksg = kt * 2 + ks;
            bf16x8 af[2], bfr[4];
#pragma unroll
            for (int mt = 0; mt < 2; ++mt) {
                int r = wr * 32 + mt * 16 + cc;
                af[mt] = *reinterpret_cast<const bf16x8*>(
                    &As[r * 256 + (((ksg * 4 + qg) ^ cc7) << 3)]);
            }
#pragma unroll
            for (int nt = 0; nt < 4; ++nt) {
                int n = wc * 64 + nt * 16 + cc;
                bfr[nt] = *reinterpret_cast<const bf16x8*>(
                    &Bs[n * 64 + (((ks * 4 + qg) ^ cc7) << 3)]);
            }
#pragma unroll
            for (int mt = 0; mt < 2; ++mt)
#pragma unroll
                for (int nt = 0; nt < 4; ++nt)
                    acc[mt][nt] = __builtin_amdgcn_mfma_f32_16x16x32_bf16(
                        af[mt], bfr[nt], acc[mt][nt], 0, 0, 0);
        }
        __syncthreads();               // waves done reading Bs slice kt
        if (kt < 3) {
            write_ab(kt + 1);          // waits on in-flight loads; As region disjoint
            if (kt < 2) { load_a(kt + 2); load_b(kt + 2); }  // overlap next MFMA
            __syncthreads();
        }
    }
    // Bs region now dead -> epilogue buffers alias it.

    // tanh + dot-V epilogue -> per-row score partials
    float Vu[4], pqu[4];
#pragma unroll
    for (int nt = 0; nt < 4; ++nt) {
        int u = wc * 64 + nt * 16 + cc;
        Vu[nt] = V[u];
        pqu[nt] = pq[b * U_ + u];
    }
#pragma unroll
    for (int mt = 0; mt < 2; ++mt) {
#pragma unroll
        for (int r = 0; r < 4; ++r) {
            float s = 0.f;
#pragma unroll
            for (int nt = 0; nt < 4; ++nt)
                s += Vu[nt] * fast_tanh(acc[mt][nt][r] + pqu[nt]);
            s += __shfl_xor(s, 1);
            s += __shfl_xor(s, 2);
            s += __shfl_xor(s, 4);
            s += __shfl_xor(s, 8);
            if (cc == 0) part[wc * 64 + wr * 32 + mt * 16 + qg * 4 + r] = s;
        }
    }
    __syncthreads();
    if (tid < 64) {
        float sc = part[tid] + part[64 + tid];
        scores[(size_t)b * S_ + s0 + tid] = sc;
        sarr[tid] = sc;
    }
    __syncthreads();
    if (tid < 64) {
        float m = sarr[tid];
#pragma unroll
        for (int off = 32; off >= 1; off >>= 1) m = fmaxf(m, __shfl_xor(m, off));
        if (tid == 0) redm[0] = m;
    }
    __syncthreads();
    float M = redm[0];
    if (tid < 64) parr[tid] = __expf(sarr[tid] - M);
    __syncthreads();
    if (tid < 64) {
        float l = parr[tid];
#pragma unroll
        for (int off = 32; off >= 1; off >>= 1) l += __shfl_xor(l, off);
        if (tid == 0) { mbuf[b * NCHUNK + cid] = M; lbuf[b * NCHUNK + cid] = l; }
    }
    __syncthreads();

    // partial context from LDS bf16 tile (wave-uniform row; conflict-free).
    int g = tid & 63, sub = tid >> 6;
    floatx4 acc4 = {0.f, 0.f, 0.f, 0.f};
#pragma unroll 4
    for (int i = 0; i < 16; ++i) {
        int r = i * 4 + sub;
        float w = parr[r];
        int addr = r * 256 + (((g >> 1) ^ (r & 7)) << 3) + (g & 1) * 4;
        ushortx4 u = *reinterpret_cast<const ushortx4*>(&As[addr]);
        acc4[0] = fmaf(bf2f(u[0]), w, acc4[0]);
        acc4[1] = fmaf(bf2f(u[1]), w, acc4[1]);
        acc4[2] = fmaf(bf2f(u[2]), w, acc4[2]);
        acc4[3] = fmaf(bf2f(u[3]), w, acc4[3]);
    }
    cbuf[tid] = acc4;
    __syncthreads();
    if (tid < 64) {
        floatx4 r4 = cbuf[tid] + cbuf[tid + 64] + cbuf[tid + 128] + cbuf[tid + 192];
        *reinterpret_cast<floatx4*>(cpart + ((size_t)b * NCHUNK + cid) * D_ + g * 4) = r4;
    }
}

// Kernel 3: grid (B_, 9). y<8: write 1024 weights; y==8: combined context.
__global__ __launch_bounds__(256) void finalize_kernel(
        const float* __restrict__ scores, const float* __restrict__ mbuf,
        const float* __restrict__ lbuf, const float* __restrict__ cpart,
        float* __restrict__ out) {
    int b = blockIdx.x;
    int part_id = blockIdx.y;
    int tid = threadIdx.x;
    __shared__ float wred[4];
    __shared__ float alpha[NCHUNK];
    if (tid < NCHUNK) {
        float m = mbuf[b * NCHUNK + tid];
#pragma unroll
        for (int off = 32; off >= 1; off >>= 1) m = fmaxf(m, __shfl_xor(m, off));
        if ((tid & 63) == 0) wred[tid >> 6] = m;
    }
    __syncthreads();
    float M = fmaxf(wred[0], wred[1]);
    if (tid < NCHUNK) {
        float z = lbuf[b * NCHUNK + tid] * __expf(mbuf[b * NCHUNK + tid] - M);
#pragma unroll
        for (int off = 32; off >= 1; off >>= 1) z += __shfl_xor(z, off);
        if ((tid & 63) == 0) wred[2 + (tid >> 6)] = z;
    }
    __syncthreads();
    float invZ = 1.f / (wred[2] + wred[3]);

    if (part_id < 8) {
        size_t off = (size_t)b * S_ + part_id * 1024;
        floatx4 v = *reinterpret_cast<const floatx4*>(scores + off + tid * 4);
        floatx4 w;
#pragma unroll
        for (int j = 0; j < 4; ++j) w[j] = __expf(v[j] - M) * invZ;
        *reinterpret_cast<floatx4*>(out + B_ * D_ + off + tid * 4) = w;
    } else {
        if (tid < NCHUNK) alpha[tid] = __expf(mbuf[b * NCHUNK + tid] - M) * invZ;
        __syncthreads();
        float acc = 0.f;
#pragma unroll 8
        for (int c = 0; c < NCHUNK; ++c)
            acc = fmaf(alpha[c], cpart[((size_t)b * NCHUNK + c) * D_ + tid], acc);
        out[b * D_ + tid] = acc;
    }
}

extern "C" void kernel_launch(void* const* d_in, const int* in_sizes, int n_in,
                              void* d_out, int out_size, void* d_ws, size_t ws_size,
                              hipStream_t stream) {
    const float* query  = (const float*)d_in[0];
    const float* values = (const float*)d_in[1];
    const float* W1     = (const float*)d_in[2];
    const float* W2     = (const float*)d_in[3];
    const float* V      = (const float*)d_in[4];
    float* out = (float*)d_out;

    char* ws = (char*)d_ws;
    unsigned short* w1t = (unsigned short*)ws;               ws += 65536;           // 64 KiB
    float* pq     = (float*)ws;                              ws += 16384;           // 16 KiB
    float* scores = (float*)ws;                              ws += B_ * S_ * 4;     // 1 MiB
    float* mbuf   = (float*)ws;                              ws += B_ * NCHUNK * 4; // 16 KiB
    float* lbuf   = (float*)ws;                              ws += B_ * NCHUNK * 4; // 16 KiB
    float* cpart  = (float*)ws;                                                    // 4 MiB

    prep_kernel<<<dim3(32), dim3(128), 0, stream>>>(query, W1, W2, pq, w1t);
    fused_kernel<<<dim3(NCHUNK, B_), dim3(256), 0, stream>>>(values, w1t, pq, V,
                                                             scores, mbuf, lbuf, cpart);
    finalize_kernel<<<dim3(B_, 9), dim3(256), 0, stream>>>(scores, mbuf, lbuf, cpart, out);
}